// Round 1
// baseline (110.308 us; speedup 1.0000x reference)
//
#include <hip/hip_runtime.h>

#define N_AQI 35
#define N_MEO 18
#define NN    53
#define F     16

__global__ __launch_bounds__(64)
void spat_disc_kernel(
    const float* __restrict__ out_aqi,   // (BT,35)
    const float* __restrict__ out_meo,   // (BT,18,3)
    const float* __restrict__ adj,       // (53,53)
    const float* __restrict__ adj_norm,  // (53,53)
    const float* __restrict__ W_trans,   // (6)
    const float* __restrict__ b_trans,   // (6)
    const float* __restrict__ W_xa,      // (6,16)
    const float* __restrict__ W_xm,      // (3,16)
    const float* __restrict__ W_ua,      // (6,16)
    const float* __restrict__ W_um,      // (3,16)
    const float* __restrict__ a_aa,      // (33)
    const float* __restrict__ a_am,
    const float* __restrict__ a_ma,
    const float* __restrict__ a_mm,
    const float* __restrict__ W_out,     // (32)
    const float* __restrict__ b_out,     // (1)
    float* __restrict__ out, int BT)
{
  const int bt  = blockIdx.x;
  const int tid = threadIdx.x;

  __shared__ float sh_wxa[F], sh_bxa[F], sh_wua[F], sh_bua[F];
  __shared__ float sh_c[8];            // cs_aa1,cs_aa0,cs_am1,cs_am0,cd_aa1,cd_aa0,cd_ma1,cd_ma0
  __shared__ float sh_v[12];           // vs_ma[3] vs_mm[3] vd_am[3] vd_mm[3]
  __shared__ float sh_l[4];            // l_aa,l_am,l_ma,l_mm
  __shared__ float sh_attri[NN * 17];  // padded rows (avoid stride-16 conflicts)
  __shared__ float sh_d[2 * N_AQI + 2 * N_MEO]; // d_aa[35]|d_ma[35]|d_am[18]|d_mm[18]
  __shared__ float sh_e[NN * NN];      // per-row edge scores (stride 53: 2-way = free)
  __shared__ float sh_ho[NN * 17];
  __shared__ float sh_sm[32];

  // ---- phase 1: effective weight vectors (rank-1 collapse of W_trans) ----
  if (tid < F) {
    float wxa = 0.f, bxa = 0.f, wua = 0.f, bua = 0.f;
    for (int k = 0; k < 6; ++k) {
      float wt = W_trans[k], btr = b_trans[k];
      wxa += wt  * W_xa[k * F + tid];
      bxa += btr * W_xa[k * F + tid];
      wua += wt  * W_ua[k * F + tid];
      bua += btr * W_ua[k * F + tid];
    }
    sh_wxa[tid] = wxa; sh_bxa[tid] = bxa;
    sh_wua[tid] = wua; sh_bua[tid] = bua;
  }
  __syncthreads();

  // ---- phase 2: scalar/3-vector attention coefficients ----
  if (tid < 8) {
    // 0:cs_aa1 1:cs_aa0 2:cs_am1 3:cs_am0 4:cd_aa1 5:cd_aa0 6:cd_ma1 7:cd_ma0
    const float* avec = (tid == 0 || tid == 1 || tid == 4 || tid == 5) ? a_aa
                       : (tid < 4 ? a_am : a_ma);
    int off = (tid < 4) ? 0 : F;
    const float* wv = (tid & 1) ? sh_bua : sh_wua;
    float acc = 0.f;
    for (int f = 0; f < F; ++f) acc += wv[f] * avec[off + f];
    sh_c[tid] = acc;
  } else if (tid < 20) {
    int t = tid - 8;          // 0..11
    int k = t % 3;            // W_um row
    int grp = t / 3;          // 0:vs_ma 1:vs_mm 2:vd_am 3:vd_mm
    const float* avec = (grp == 0) ? a_ma : (grp == 1) ? a_mm
                       : (grp == 2) ? a_am : a_mm;
    int off = (grp < 2) ? 0 : F;
    float acc = 0.f;
    for (int f = 0; f < F; ++f) acc += W_um[k * F + f] * avec[off + f];
    sh_v[t] = acc;
  } else if (tid < 24) {
    const float* avec = (tid == 20) ? a_aa : (tid == 21) ? a_am
                       : (tid == 22) ? a_ma : a_mm;
    sh_l[tid - 20] = avec[2 * F];
  }
  __syncthreads();

  // ---- row phase: per-node s/d scalars + heter_attri row ----
  float s_a = 0.f, s_m = 0.f, l_a = 0.f, l_m = 0.f;
  if (tid < N_AQI) {
    float x = out_aqi[bt * N_AQI + tid];
    s_a = sh_c[0] * x + sh_c[1];            // src via a_aa[:16]
    s_m = sh_c[2] * x + sh_c[3];            // src via a_am[:16]
    sh_d[tid]         = sh_c[4] * x + sh_c[5];  // dst via a_aa[16:32]
    sh_d[N_AQI + tid] = sh_c[6] * x + sh_c[7];  // dst via a_ma[16:32]
    for (int f = 0; f < F; ++f)
      sh_attri[tid * 17 + f] = sh_wxa[f] * x + sh_bxa[f];
    l_a = sh_l[0]; l_m = sh_l[1];
  } else if (tid < NN) {
    int m = tid - N_AQI;
    float m0 = out_meo[(bt * N_MEO + m) * 3 + 0];
    float m1 = out_meo[(bt * N_MEO + m) * 3 + 1];
    float m2 = out_meo[(bt * N_MEO + m) * 3 + 2];
    s_a = m0 * sh_v[0] + m1 * sh_v[1]  + m2 * sh_v[2];   // src via a_ma[:16]
    s_m = m0 * sh_v[3] + m1 * sh_v[4]  + m2 * sh_v[5];   // src via a_mm[:16]
    sh_d[2 * N_AQI + m]         = m0 * sh_v[6] + m1 * sh_v[7]  + m2 * sh_v[8];  // a_am[16:32]
    sh_d[2 * N_AQI + N_MEO + m] = m0 * sh_v[9] + m1 * sh_v[10] + m2 * sh_v[11]; // a_mm[16:32]
    for (int f = 0; f < F; ++f)
      sh_attri[tid * 17 + f] = m0 * W_xm[0 * F + f] + m1 * W_xm[1 * F + f] + m2 * W_xm[2 * F + f];
    l_a = sh_l[2]; l_m = sh_l[3];
  }
  __syncthreads();

  // ---- masked softmax + PV, one row per thread ----
  if (tid < NN) {
    const int i = tid;
    const float* adj_row = adj + i * NN;
    const float* an_row  = adj_norm + i * NN;
    float mx = -1e30f;
    for (int j = 0; j < NN; ++j) {
      float e;
      if (adj_row[j] > 0.0f) {
        float dv = (j < N_AQI)
                     ? ((i < N_AQI) ? sh_d[j] : sh_d[N_AQI + j])
                     : ((i < N_AQI) ? sh_d[2 * N_AQI + (j - N_AQI)]
                                    : sh_d[2 * N_AQI + N_MEO + (j - N_AQI)]);
        float sv = (j < N_AQI) ? s_a : s_m;
        float lv = (j < N_AQI) ? l_a : l_m;
        float z = sv + dv + an_row[j] * lv;
        e = (z > 0.0f) ? z : 0.2f * z;       // leaky relu, alpha=0.2
        if (e > mx) mx = e;
      } else {
        e = -INFINITY;                        // exp -> exact 0
      }
      sh_e[i * NN + j] = e;
    }
    float acc[F];
#pragma unroll
    for (int f = 0; f < F; ++f) acc[f] = 0.f;
    float lsum = 0.f;
    for (int j = 0; j < NN; ++j) {
      float w = __expf(sh_e[i * NN + j] - mx);
      lsum += w;
#pragma unroll
      for (int f = 0; f < F; ++f) acc[f] += w * sh_attri[j * 17 + f];
    }
    float inv = 1.0f / lsum;
#pragma unroll
    for (int f = 0; f < F; ++f) sh_ho[i * 17 + f] = acc[f] * inv;
  }
  __syncthreads();

  // ---- means over node groups + sigmoid -> out_smetric ----
  if (tid < 32) {
    float s = 0.f;
    if (tid < F) {
      for (int i = 0; i < N_AQI; ++i) s += sh_ho[i * 17 + tid];
      s *= (1.0f / N_AQI);
    } else {
      int f = tid - F;
      for (int i = N_AQI; i < NN; ++i) s += sh_ho[i * 17 + f];
      s *= (1.0f / N_MEO);
    }
    float sm = 1.0f / (1.0f + __expf(-s));
    sh_sm[tid] = sm;
    out[BT + bt * 32 + tid] = sm;            // out_smetric (after the BT sscore block)
  }
  __syncthreads();

  // ---- final score ----
  if (tid == 0) {
    float z = b_out[0];
    for (int k = 0; k < 32; ++k) z += sh_sm[k] * W_out[k];
    out[bt] = 1.0f / (1.0f + __expf(-z));
  }
}

extern "C" void kernel_launch(void* const* d_in, const int* in_sizes, int n_in,
                              void* d_out, int out_size, void* d_ws, size_t ws_size,
                              hipStream_t stream) {
  const float* out_aqi  = (const float*)d_in[0];
  const float* out_meo  = (const float*)d_in[1];
  const float* adj      = (const float*)d_in[2];
  const float* adj_norm = (const float*)d_in[3];
  const float* W_trans  = (const float*)d_in[4];
  const float* b_trans  = (const float*)d_in[5];
  const float* W_xa     = (const float*)d_in[6];
  const float* W_xm     = (const float*)d_in[7];
  const float* W_ua     = (const float*)d_in[8];
  const float* W_um     = (const float*)d_in[9];
  const float* a_aa     = (const float*)d_in[10];
  const float* a_am     = (const float*)d_in[11];
  const float* a_ma     = (const float*)d_in[12];
  const float* a_mm     = (const float*)d_in[13];
  const float* W_out    = (const float*)d_in[14];
  const float* b_out    = (const float*)d_in[15];
  float* out = (float*)d_out;

  const int BT = in_sizes[0] / N_AQI;   // 1024

  spat_disc_kernel<<<BT, 64, 0, stream>>>(
      out_aqi, out_meo, adj, adj_norm, W_trans, b_trans,
      W_xa, W_xm, W_ua, W_um, a_aa, a_am, a_ma, a_mm, W_out, b_out,
      out, BT);
}

// Round 4
// 99.184 us; speedup vs baseline: 1.1122x; 1.1122x over previous
//
#include <hip/hip_runtime.h>

#define N_AQI 35
#define N_MEO 18
#define NN    53
#define F     16
#define AP    20   // attri row padding (floats) -> 16B-aligned float4 reads

__global__ __launch_bounds__(256)
void spat_disc_kernel(
    const float* __restrict__ out_aqi,   // (BT,35)
    const float* __restrict__ out_meo,   // (BT,18,3)
    const float* __restrict__ adj,       // (53,53)
    const float* __restrict__ adj_norm,  // (53,53)
    const float* __restrict__ W_trans,   // (6)
    const float* __restrict__ b_trans,   // (6)
    const float* __restrict__ W_xa,      // (6,16)
    const float* __restrict__ W_xm,      // (3,16)
    const float* __restrict__ W_ua,      // (6,16)
    const float* __restrict__ W_um,      // (3,16)
    const float* __restrict__ a_aa,      // (33)
    const float* __restrict__ a_am,
    const float* __restrict__ a_ma,
    const float* __restrict__ a_mm,
    const float* __restrict__ W_out,     // (32)
    const float* __restrict__ b_out,     // (1)
    float* __restrict__ out, int BT)
{
  const int bt  = blockIdx.x;
  const int tid = threadIdx.x;
  const int i   = tid >> 2;     // row 0..63 (active < 53)
  const int fq  = tid & 3;      // feature quartet

  __shared__ float sh_wxa[F], sh_bxa[F], sh_wua[F], sh_bua[F];
  __shared__ float sh_c[8];            // cs_aa1,cs_aa0,cs_am1,cs_am0,cd_aa1,cd_aa0,cd_ma1,cd_ma0
  __shared__ float sh_v[12];           // vs_ma[3] vs_mm[3] vd_am[3] vd_mm[3]
  __shared__ float sh_l[4];            // l_aa,l_am,l_ma,l_mm
  __shared__ float sh_dA[NN];          // dst-scalar for rows i<35
  __shared__ float sh_dM[NN];          // dst-scalar for rows i>=35
  __shared__ float sh_attri[NN * AP];
  __shared__ float sh_P[NN * NN];      // adj>0 ? adj_norm*l_quad : -INF
  __shared__ float sh_ho[NN * AP];
  __shared__ float sh_sm[32];

  // ---- phase 1: rank-1 collapse of W_trans into effective 16-vectors ----
  if (tid < F) {
    float wxa = 0.f, bxa = 0.f, wua = 0.f, bua = 0.f;
    for (int k = 0; k < 6; ++k) {
      float wt = W_trans[k], btr = b_trans[k];
      wxa += wt  * W_xa[k * F + tid];
      bxa += btr * W_xa[k * F + tid];
      wua += wt  * W_ua[k * F + tid];
      bua += btr * W_ua[k * F + tid];
    }
    sh_wxa[tid] = wxa; sh_bxa[tid] = bxa;
    sh_wua[tid] = wua; sh_bua[tid] = bua;
  }
  __syncthreads();

  // ---- phase 2: scalar/3-vector attention coefficients ----
  if (tid < 8) {
    const float* avec = (tid == 0 || tid == 1 || tid == 4 || tid == 5) ? a_aa
                       : (tid < 4 ? a_am : a_ma);
    int off = (tid < 4) ? 0 : F;
    const float* wv = (tid & 1) ? sh_bua : sh_wua;
    float acc = 0.f;
    for (int f = 0; f < F; ++f) acc += wv[f] * avec[off + f];
    sh_c[tid] = acc;
  } else if (tid < 20) {
    int t = tid - 8;
    int k = t % 3;
    int grp = t / 3;          // 0:vs_ma 1:vs_mm 2:vd_am 3:vd_mm
    const float* avec = (grp == 0) ? a_ma : (grp == 1) ? a_mm
                       : (grp == 2) ? a_am : a_mm;
    int off = (grp < 2) ? 0 : F;
    float acc = 0.f;
    for (int f = 0; f < F; ++f) acc += W_um[k * F + f] * avec[off + f];
    sh_v[t] = acc;
  } else if (tid < 24) {
    const float* avec = (tid == 20) ? a_aa : (tid == 21) ? a_am
                       : (tid == 22) ? a_ma : a_mm;
    sh_l[tid - 20] = avec[2 * F];
  }
  __syncthreads();

  // ---- node phase (tid<53): dst scalars + attri row; all: P staging + src scalars ----
  if (tid < NN) {
    if (tid < N_AQI) {
      float x = out_aqi[bt * N_AQI + tid];
      sh_dA[tid] = sh_c[4] * x + sh_c[5];   // a_aa dst
      sh_dM[tid] = sh_c[6] * x + sh_c[7];   // a_ma dst
      for (int f = 0; f < F; ++f)
        sh_attri[tid * AP + f] = sh_wxa[f] * x + sh_bxa[f];
    } else {
      int m = tid - N_AQI;
      float m0 = out_meo[(bt * N_MEO + m) * 3 + 0];
      float m1 = out_meo[(bt * N_MEO + m) * 3 + 1];
      float m2 = out_meo[(bt * N_MEO + m) * 3 + 2];
      sh_dA[tid] = m0 * sh_v[6] + m1 * sh_v[7]  + m2 * sh_v[8];   // a_am dst
      sh_dM[tid] = m0 * sh_v[9] + m1 * sh_v[10] + m2 * sh_v[11];  // a_mm dst
      for (int f = 0; f < F; ++f)
        sh_attri[tid * AP + f] = m0 * W_xm[0 * F + f] + m1 * W_xm[1 * F + f] + m2 * W_xm[2 * F + f];
    }
  }
  // masked P table (coalesced global reads, no branches later)
  for (int t = tid; t < NN * NN; t += 256) {
    int ii = t / NN;
    int jj = t - ii * NN;
    float a  = adj[t];
    float an = adj_norm[t];
    float l  = (ii < N_AQI) ? ((jj < N_AQI) ? sh_l[0] : sh_l[1])
                            : ((jj < N_AQI) ? sh_l[2] : sh_l[3]);
    sh_P[t] = (a > 0.f) ? an * l : -INFINITY;
  }
  // per-thread src scalars for row i
  float s0 = 0.f, s1 = 0.f;
  if (i < NN) {
    if (i < N_AQI) {
      float x = out_aqi[bt * N_AQI + i];
      s0 = sh_c[0] * x + sh_c[1];           // a_aa src (j<35)
      s1 = sh_c[2] * x + sh_c[3];           // a_am src (j>=35)
    } else {
      int m = i - N_AQI;
      float m0 = out_meo[(bt * N_MEO + m) * 3 + 0];
      float m1 = out_meo[(bt * N_MEO + m) * 3 + 1];
      float m2 = out_meo[(bt * N_MEO + m) * 3 + 2];
      s0 = m0 * sh_v[0] + m1 * sh_v[1] + m2 * sh_v[2];   // a_ma src
      s1 = m0 * sh_v[3] + m1 * sh_v[4] + m2 * sh_v[5];   // a_mm src
    }
  }
  __syncthreads();

  // ---- single-pass no-max softmax + PV: thread (i, fq) owns 4 features ----
  if (i < NN) {
    const float* dbase = (i < N_AQI) ? sh_dA : sh_dM;
    const float* Prow  = sh_P + i * NN;
    float a0 = 0.f, a1 = 0.f, a2 = 0.f, a3 = 0.f, lsum = 0.f;
#pragma unroll 1
    for (int j = 0; j < NN; ++j) {
      float z = ((j < N_AQI) ? s0 : s1) + dbase[j] + Prow[j];
      float e = (z > 0.0f) ? z : 0.2f * z;      // leaky relu; -INF stays -INF
      float w = __expf(e);                       // masked -> exact 0
      lsum += w;
      const float4 av = *(const float4*)(sh_attri + j * AP + fq * 4);
      a0 += w * av.x; a1 += w * av.y; a2 += w * av.z; a3 += w * av.w;
    }
    float inv = 1.0f / lsum;
    float4* hrow = (float4*)(sh_ho + i * AP + fq * 4);
    *hrow = make_float4(a0 * inv, a1 * inv, a2 * inv, a3 * inv);
  }
  __syncthreads();

  // ---- group means + sigmoid -> out_smetric ----
  if (tid < 32) {
    float s = 0.f;
    if (tid < F) {
      for (int r = 0; r < N_AQI; ++r) s += sh_ho[r * AP + tid];
      s *= (1.0f / N_AQI);
    } else {
      int f = tid - F;
      for (int r = N_AQI; r < NN; ++r) s += sh_ho[r * AP + f];
      s *= (1.0f / N_MEO);
    }
    float sm = 1.0f / (1.0f + __expf(-s));
    sh_sm[tid] = sm;
    out[BT + bt * 32 + tid] = sm;
  }
  __syncthreads();

  // ---- final score ----
  if (tid == 0) {
    float z = b_out[0];
    for (int k = 0; k < 32; ++k) z += sh_sm[k] * W_out[k];
    out[bt] = 1.0f / (1.0f + __expf(-z));
  }
}

extern "C" void kernel_launch(void* const* d_in, const int* in_sizes, int n_in,
                              void* d_out, int out_size, void* d_ws, size_t ws_size,
                              hipStream_t stream) {
  const float* out_aqi  = (const float*)d_in[0];
  const float* out_meo  = (const float*)d_in[1];
  const float* adj      = (const float*)d_in[2];
  const float* adj_norm = (const float*)d_in[3];
  const float* W_trans  = (const float*)d_in[4];
  const float* b_trans  = (const float*)d_in[5];
  const float* W_xa     = (const float*)d_in[6];
  const float* W_xm     = (const float*)d_in[7];
  const float* W_ua     = (const float*)d_in[8];
  const float* W_um     = (const float*)d_in[9];
  const float* a_aa     = (const float*)d_in[10];
  const float* a_am     = (const float*)d_in[11];
  const float* a_ma     = (const float*)d_in[12];
  const float* a_mm     = (const float*)d_in[13];
  const float* W_out    = (const float*)d_in[14];
  const float* b_out    = (const float*)d_in[15];
  float* out = (float*)d_out;

  const int BT = in_sizes[0] / N_AQI;   // 1024

  spat_disc_kernel<<<BT, 256, 0, stream>>>(
      out_aqi, out_meo, adj, adj_norm, W_trans, b_trans,
      W_xa, W_xm, W_ua, W_um, a_aa, a_am, a_ma, a_mm, W_out, b_out,
      out, BT);
}

// Round 5
// 96.955 us; speedup vs baseline: 1.1377x; 1.0230x over previous
//
#include <hip/hip_runtime.h>

#define N_AQI 35
#define N_MEO 18
#define NN    53
#define F     16
#define AP    20     // attri row padding (floats) -> 16B-aligned float4 reads
#define P_OFF 64     // P table offset (floats) inside d_ws

// ---------------- kernel A: bt-invariant precompute (runs once per call) ----
// wsf[0..7]   c   : cs_aa1,cs_aa0,cs_am1,cs_am0,cd_aa1,cd_aa0,cd_ma1,cd_ma0
// wsf[8..19]  v   : vs_ma[3] vs_mm[3] vd_am[3] vd_mm[3]
// wsf[20..35] wxa ; wsf[36..51] bxa
// wsf[P_OFF .. P_OFF+2808] : P[i*53+j] = adj>0 ? adj_norm*l_quad : -INF
__global__ __launch_bounds__(256)
void precompute_kernel(
    const float* __restrict__ adj, const float* __restrict__ adj_norm,
    const float* __restrict__ W_trans, const float* __restrict__ b_trans,
    const float* __restrict__ W_xa, const float* __restrict__ W_ua,
    const float* __restrict__ W_um,
    const float* __restrict__ a_aa, const float* __restrict__ a_am,
    const float* __restrict__ a_ma, const float* __restrict__ a_mm,
    float* __restrict__ wsf)
{
  const int tid = threadIdx.x;
  __shared__ float s_wua[F], s_bua[F];

  if (blockIdx.x == 0) {
    if (tid < F) {
      float wxa = 0.f, bxa = 0.f, wua = 0.f, bua = 0.f;
      for (int k = 0; k < 6; ++k) {
        float wt = W_trans[k], btr = b_trans[k];
        wxa += wt  * W_xa[k * F + tid];
        bxa += btr * W_xa[k * F + tid];
        wua += wt  * W_ua[k * F + tid];
        bua += btr * W_ua[k * F + tid];
      }
      s_wua[tid] = wua; s_bua[tid] = bua;
      wsf[20 + tid] = wxa; wsf[36 + tid] = bxa;
    }
    __syncthreads();
    if (tid < 8) {
      const float* avec = (tid == 0 || tid == 1 || tid == 4 || tid == 5) ? a_aa
                         : (tid < 4 ? a_am : a_ma);
      int off = (tid < 4) ? 0 : F;
      const float* wv = (tid & 1) ? s_bua : s_wua;
      float acc = 0.f;
      for (int f = 0; f < F; ++f) acc += wv[f] * avec[off + f];
      wsf[tid] = acc;
    } else if (tid < 20) {
      int t = tid - 8;
      int k = t % 3;
      int grp = t / 3;          // 0:vs_ma 1:vs_mm 2:vd_am 3:vd_mm
      const float* avec = (grp == 0) ? a_ma : (grp == 1) ? a_mm
                         : (grp == 2) ? a_am : a_mm;
      int off = (grp < 2) ? 0 : F;
      float acc = 0.f;
      for (int f = 0; f < F; ++f) acc += W_um[k * F + f] * avec[off + f];
      wsf[8 + t] = acc;
    }
  }

  // P table (all 8 blocks; l-values loaded directly, no cross-block dep)
  const float l0 = a_aa[2 * F], l1 = a_am[2 * F], l2 = a_ma[2 * F], l3 = a_mm[2 * F];
  for (int t = blockIdx.x * 256 + tid; t < NN * NN; t += 8 * 256) {
    int ii = t / NN;
    int jj = t - ii * NN;
    float l = (ii < N_AQI) ? ((jj < N_AQI) ? l0 : l1)
                           : ((jj < N_AQI) ? l2 : l3);
    wsf[P_OFF + t] = (adj[t] > 0.f) ? adj_norm[t] * l : -INFINITY;
  }
}

// ---------------- kernel B: per-bt main ----------------
__global__ __launch_bounds__(256)
void spat_disc_kernel(
    const float* __restrict__ out_aqi,   // (BT,35)
    const float* __restrict__ out_meo,   // (BT,18,3)
    const float* __restrict__ W_xm,      // (3,16)
    const float* __restrict__ W_out,     // (32)
    const float* __restrict__ b_out,     // (1)
    const float* __restrict__ wsf,       // precomputed constants + P
    float* __restrict__ out, int BT)
{
  const int bt  = blockIdx.x;
  const int tid = threadIdx.x;
  const int i   = tid >> 2;     // row 0..63 (active < 53)
  const int fq  = tid & 3;      // feature quartet

  __shared__ float shc[52];            // c[8] v[12] wxa[16] bxa[16]
  __shared__ float sh_dA[NN];          // dst-scalar used by rows i<35
  __shared__ float sh_dM[NN];          // dst-scalar used by rows i>=35
  __shared__ float sh_attri[NN * AP];
  __shared__ float sh_ho[NN * AP];

  if (tid < 52) shc[tid] = wsf[tid];
  __syncthreads();

  // ---- node phase: dst scalars + attri rows ----
  if (tid < NN) {
    if (tid < N_AQI) {
      float x = out_aqi[bt * N_AQI + tid];
      sh_dA[tid] = shc[4] * x + shc[5];   // a_aa dst
      sh_dM[tid] = shc[6] * x + shc[7];   // a_ma dst
      for (int f = 0; f < F; ++f)
        sh_attri[tid * AP + f] = shc[20 + f] * x + shc[36 + f];
    } else {
      int m = tid - N_AQI;
      float m0 = out_meo[(bt * N_MEO + m) * 3 + 0];
      float m1 = out_meo[(bt * N_MEO + m) * 3 + 1];
      float m2 = out_meo[(bt * N_MEO + m) * 3 + 2];
      sh_dA[tid] = m0 * shc[8 + 6] + m1 * shc[8 + 7]  + m2 * shc[8 + 8];   // a_am dst
      sh_dM[tid] = m0 * shc[8 + 9] + m1 * shc[8 + 10] + m2 * shc[8 + 11];  // a_mm dst
      for (int f = 0; f < F; ++f)
        sh_attri[tid * AP + f] = m0 * W_xm[0 * F + f] + m1 * W_xm[1 * F + f] + m2 * W_xm[2 * F + f];
    }
  }
  // per-thread src scalars for row i
  float s0 = 0.f, s1 = 0.f;
  if (i < NN) {
    if (i < N_AQI) {
      float x = out_aqi[bt * N_AQI + i];
      s0 = shc[0] * x + shc[1];           // a_aa src (j<35)
      s1 = shc[2] * x + shc[3];           // a_am src (j>=35)
    } else {
      int m = i - N_AQI;
      float m0 = out_meo[(bt * N_MEO + m) * 3 + 0];
      float m1 = out_meo[(bt * N_MEO + m) * 3 + 1];
      float m2 = out_meo[(bt * N_MEO + m) * 3 + 2];
      s0 = m0 * shc[8 + 0] + m1 * shc[8 + 1] + m2 * shc[8 + 2];   // a_ma src
      s1 = m0 * shc[8 + 3] + m1 * shc[8 + 4] + m2 * shc[8 + 5];   // a_mm src
    }
  }
  __syncthreads();

  // ---- single-pass no-max softmax + PV; P read straight from L1-resident ws ----
  if (i < NN) {
    const float* __restrict__ dbase = (i < N_AQI) ? sh_dA : sh_dM;
    const float* __restrict__ Prow  = wsf + P_OFF + i * NN;
    float a0 = 0.f, a1 = 0.f, a2 = 0.f, a3 = 0.f, lsum = 0.f;
#pragma unroll 4
    for (int j = 0; j < NN; ++j) {
      float z = ((j < N_AQI) ? s0 : s1) + dbase[j] + Prow[j];
      float e = (z > 0.0f) ? z : 0.2f * z;      // leaky relu; -INF stays -INF
      float w = __expf(e);                       // masked -> exact 0
      lsum += w;
      const float4 av = *(const float4*)(sh_attri + j * AP + fq * 4);
      a0 += w * av.x; a1 += w * av.y; a2 += w * av.z; a3 += w * av.w;
    }
    float inv = 1.0f / lsum;
    float4* hrow = (float4*)(sh_ho + i * AP + fq * 4);
    *hrow = make_float4(a0 * inv, a1 * inv, a2 * inv, a3 * inv);
  }
  __syncthreads();

  // ---- group means + sigmoid -> out_smetric; final score via wave reduce ----
  if (tid < 32) {
    float s = 0.f;
    if (tid < F) {
      for (int r = 0; r < N_AQI; ++r) s += sh_ho[r * AP + tid];
      s *= (1.0f / N_AQI);
    } else {
      int f = tid - F;
      for (int r = N_AQI; r < NN; ++r) s += sh_ho[r * AP + f];
      s *= (1.0f / N_MEO);
    }
    float sm = 1.0f / (1.0f + __expf(-s));
    out[BT + bt * 32 + tid] = sm;               // out_smetric block

    // final: z = sum_k sm[k]*W_out[k] across lanes 0..31 of wave 0
    float zc = sm * W_out[tid];
    for (int m = 16; m > 0; m >>= 1) zc += __shfl_xor(zc, m, 32);
    if (tid == 0)
      out[bt] = 1.0f / (1.0f + __expf(-(zc + b_out[0])));
  }
}

extern "C" void kernel_launch(void* const* d_in, const int* in_sizes, int n_in,
                              void* d_out, int out_size, void* d_ws, size_t ws_size,
                              hipStream_t stream) {
  const float* out_aqi  = (const float*)d_in[0];
  const float* out_meo  = (const float*)d_in[1];
  const float* adj      = (const float*)d_in[2];
  const float* adj_norm = (const float*)d_in[3];
  const float* W_trans  = (const float*)d_in[4];
  const float* b_trans  = (const float*)d_in[5];
  const float* W_xa     = (const float*)d_in[6];
  const float* W_xm     = (const float*)d_in[7];
  const float* W_ua     = (const float*)d_in[8];
  const float* W_um     = (const float*)d_in[9];
  const float* a_aa     = (const float*)d_in[10];
  const float* a_am     = (const float*)d_in[11];
  const float* a_ma     = (const float*)d_in[12];
  const float* a_mm     = (const float*)d_in[13];
  const float* W_out    = (const float*)d_in[14];
  const float* b_out    = (const float*)d_in[15];
  float* out = (float*)d_out;
  float* wsf = (float*)d_ws;

  const int BT = in_sizes[0] / N_AQI;   // 1024

  precompute_kernel<<<8, 256, 0, stream>>>(
      adj, adj_norm, W_trans, b_trans, W_xa, W_ua, W_um,
      a_aa, a_am, a_ma, a_mm, wsf);

  spat_disc_kernel<<<BT, 256, 0, stream>>>(
      out_aqi, out_meo, W_xm, W_out, b_out, wsf, out, BT);
}